// Round 1
// 465.526 us; speedup vs baseline: 1.0322x; 1.0322x over previous
//
#include <hip/hip_runtime.h>
#include <math.h>

#define D 128
#define BLOCKS_A 768   // phase A: 2 blocks/CU resident (VGPR-bound), 3 queued/CU
#define BLOCKS_C 1024  // phase C: small kernel, 4 blocks/CU -> 4 waves/SIMD
#define THREADS 256

typedef short s8v __attribute__((ext_vector_type(8)));
typedef float f4v __attribute__((ext_vector_type(4)));

__device__ __forceinline__ float fast_tanh(float z) {
    float e = __expf(2.f * z);
    return 1.f - 2.f / (e + 1.f);
}
// 1 VALU instr for 2 f32->bf16 (vs ~5 instr/value manual round-and-shift)
__device__ __forceinline__ unsigned cvt_pk_bf16(float lo, float hi) {
    unsigned r;
    asm("v_cvt_pk_bf16_f32 %0, %1, %2" : "=v"(r) : "v"(lo), "v"(hi));
    return r;
}
__device__ __forceinline__ float bf2f(unsigned short h) {
    union { unsigned u; float f; } v; v.u = ((unsigned)h) << 16;
    return v.f;
}
__device__ __forceinline__ s8v pack8(float4 w0, float4 w1) {
    union { unsigned u[4]; s8v v; } r;
    r.u[0] = cvt_pk_bf16(w0.x, w0.y);
    r.u[1] = cvt_pk_bf16(w0.z, w0.w);
    r.u[2] = cvt_pk_bf16(w1.x, w1.y);
    r.u[3] = cvt_pk_bf16(w1.z, w1.w);
    return r.v;
}

// Phase A epilogue for one C-row-group RG_ (literal 0..3):
// y = x*(1+tanh(z)); store y as bf16 to x2s (layout: [tile][rg][lane] uint4,
// perfectly coalesced and identical to phase C's read pattern); accumulate
// per-lane running segment sums (flush via atomics on boundary).
#define EPI0(RG_)                                                             \
    {                                                                         \
        int r = R + quad * 4 + RG_;                                           \
        int seg = batch[r];                                                   \
        float yv[8];                                                          \
        _Pragma("unroll")                                                     \
        for (int t = 0; t < 8; ++t) {                                         \
            float xf = bf2f(xw[(quad * 4 + RG_) * 136 + m15 + 16 * t]);       \
            float z = af[t][RG_] + b2l[t];                                    \
            yv[t] = xf * (1.f + fast_tanh(z));                                \
        }                                                                     \
        union { unsigned u[4]; uint4 q; } pk;                                 \
        pk.u[0] = cvt_pk_bf16(yv[0], yv[1]);                                  \
        pk.u[1] = cvt_pk_bf16(yv[2], yv[3]);                                  \
        pk.u[2] = cvt_pk_bf16(yv[4], yv[5]);                                  \
        pk.u[3] = cvt_pk_bf16(yv[6], yv[7]);                                  \
        ((uint4*)x2s)[(size_t)b * 256 + RG_ * 64 + lane] = pk.q;              \
        if (seg != cur) {                                                     \
            if (cur >= 0) {                                                   \
                _Pragma("unroll")                                             \
                for (int t = 0; t < 8; ++t)                                   \
                    atomicAdd(&sums[cur * 128 + m15 + 16 * t], acc[t]);       \
                if (m15 == 0) atomicAdd(&cnt[cur], acnt);                     \
            }                                                                 \
            cur = seg;                                                        \
            _Pragma("unroll")                                                 \
            for (int t = 0; t < 8; ++t) acc[t] = yv[t];                       \
            acnt = 1.f;                                                       \
        } else {                                                              \
            _Pragma("unroll")                                                 \
            for (int t = 0; t < 8; ++t) acc[t] += yv[t];                      \
            acnt += 1.f;                                                      \
        }                                                                     \
    }

// Phase A: x2 = x*(1+tanh(MLP(x))); segment sums + counts; x2 cached as bf16.
// MFMA 16x16x32 bf16, weights in registers, 16-row tiles per wave, no
// __syncthreads (wave-private LDS, in-order DS). Next-tile x is register-
// prefetched so HBM latency hides under MFMA+epilogue of the current tile.
__global__ __launch_bounds__(THREADS, 2) void phaseA(
    const float* __restrict__ x, const int* __restrict__ batch,
    const float* __restrict__ fc1_w, const float* __restrict__ fc1_b,
    const float* __restrict__ fc2_w, const float* __restrict__ fc2_b,
    float* __restrict__ sums, float* __restrict__ cnt,
    unsigned short* __restrict__ x2s, int N)
{
    __shared__ unsigned short xbf[4][16 * 136]; // bf16 x rows, pitch 136
    __shared__ float hbuf[4][16 * 36];          // f32 hidden, pitch 36

    const int lane = threadIdx.x & 63;
    const int wv = threadIdx.x >> 6;
    const int m15 = lane & 15;
    const int quad = lane >> 4;

    // --- Weight B-fragments in registers (loop-invariant) ---
    s8v B1[2][4];
    #pragma unroll
    for (int t = 0; t < 2; ++t)
        #pragma unroll
        for (int kc = 0; kc < 4; ++kc) {
            const float* p = fc1_w + (16 * t + m15) * 128 + kc * 32 + quad * 8;
            B1[t][kc] = pack8(*(const float4*)p, *(const float4*)(p + 4));
        }
    s8v B2[8];
    #pragma unroll
    for (int t = 0; t < 8; ++t) {
        const float* p = fc2_w + (16 * t + m15) * 32 + quad * 8;
        B2[t] = pack8(*(const float4*)p, *(const float4*)(p + 4));
    }
    float b1l[2], b2l[8];
    #pragma unroll
    for (int t = 0; t < 2; ++t) b1l[t] = fc1_b[m15 + 16 * t];
    #pragma unroll
    for (int t = 0; t < 8; ++t) b2l[t] = fc2_b[m15 + 16 * t];

    // --- Balanced contiguous 16-row blocks per wave ---
    const int total16 = N >> 4;
    const int nw = BLOCKS_A * 4;
    const int gw = blockIdx.x * 4 + wv;
    const int base = total16 / nw, rem = total16 % nw;
    const int b0 = gw * base + (gw < rem ? gw : rem);
    const int b1e = b0 + base + (gw < rem ? 1 : 0);

    unsigned short* xw = xbf[wv];
    float* hw = hbuf[wv];

    float acc[8];
    #pragma unroll
    for (int t = 0; t < 8; ++t) acc[t] = 0.f;
    int cur = -1;
    float acnt = 0.f;
    const f4v z4 = {0.f, 0.f, 0.f, 0.f};

    // software pipeline: L holds the in-flight x tile (32 VGPRs)
    float4 L[8];
    if (b0 < b1e) {
        const float* xp = x + (size_t)(b0 << 4) * D;
        #pragma unroll
        for (int u = 0; u < 8; ++u)
            L[u] = *(const float4*)(xp + u * 256 + lane * 4);
    }

    for (int b = b0; b < b1e; ++b) {
        const int R = b << 4;
        // convert arrived tile to packed bf16 (frees L), then issue next loads
        uint2 P[8];
        #pragma unroll
        for (int u = 0; u < 8; ++u) {
            P[u].x = cvt_pk_bf16(L[u].x, L[u].y);
            P[u].y = cvt_pk_bf16(L[u].z, L[u].w);
        }
        if (b + 1 < b1e) {
            const float* xp = x + (size_t)((b + 1) << 4) * D;
            #pragma unroll
            for (int u = 0; u < 8; ++u)
                L[u] = *(const float4*)(xp + u * 256 + lane * 4);
        }
        #pragma unroll
        for (int u = 0; u < 8; ++u) {
            int row = 2 * u + (lane >> 5);
            int col = (lane & 31) * 4;
            *(uint2*)&xw[row * 136 + col] = P[u];
        }
        // A-fragments of x
        s8v ax[4];
        #pragma unroll
        for (int kc = 0; kc < 4; ++kc)
            ax[kc] = *(const s8v*)&xw[m15 * 136 + kc * 32 + quad * 8];
        // GEMM1: h[16][32] = x @ W1^T
        f4v accH[2];
        accH[0] = z4; accH[1] = z4;
        #pragma unroll
        for (int kc = 0; kc < 4; ++kc) {
            accH[0] = __builtin_amdgcn_mfma_f32_16x16x32_bf16(ax[kc], B1[0][kc], accH[0], 0, 0, 0);
            accH[1] = __builtin_amdgcn_mfma_f32_16x16x32_bf16(ax[kc], B1[1][kc], accH[1], 0, 0, 0);
        }
        // bias + ReLU -> LDS
        #pragma unroll
        for (int t = 0; t < 2; ++t)
            #pragma unroll
            for (int rg = 0; rg < 4; ++rg) {
                float hv = fmaxf(accH[t][rg] + b1l[t], 0.f);
                hw[(quad * 4 + rg) * 36 + m15 + 16 * t] = hv;
            }
        // A-fragment of h
        const f4v h0 = *(const f4v*)&hw[m15 * 36 + quad * 8];
        const f4v h1 = *(const f4v*)&hw[m15 * 36 + quad * 8 + 4];
        union { unsigned u[4]; s8v v; } ahu;
        ahu.u[0] = cvt_pk_bf16(h0[0], h0[1]);
        ahu.u[1] = cvt_pk_bf16(h0[2], h0[3]);
        ahu.u[2] = cvt_pk_bf16(h1[0], h1[1]);
        ahu.u[3] = cvt_pk_bf16(h1[2], h1[3]);
        s8v ah = ahu.v;
        // GEMM2: a[16][128] = h @ W2^T
        f4v af[8];
        #pragma unroll
        for (int t = 0; t < 8; ++t)
            af[t] = __builtin_amdgcn_mfma_f32_16x16x32_bf16(ah, B2[t], z4, 0, 0, 0);

        EPI0(0) EPI0(1) EPI0(2) EPI0(3)
    }
    if (cur >= 0) {
        #pragma unroll
        for (int t = 0; t < 8; ++t)
            atomicAdd(&sums[cur * 128 + m15 + 16 * t], acc[t]);
        if (m15 == 0) atomicAdd(&cnt[cur], acnt);
    }
}

// tg = tanh((sums/max(cnt,1)) @ Wm), one 128-thread block per segment
__global__ __launch_bounds__(D, 8) void phaseB(
    const float* __restrict__ sums, const float* __restrict__ cnt,
    const float* __restrict__ Wm, float* __restrict__ tg)
{
    int b = blockIdx.x;
    int d = threadIdx.x;
    __shared__ float m[D];
    float inv = 1.f / fmaxf(cnt[b], 1.f);
    m[d] = sums[(b << 7) + d] * inv;
    __syncthreads();
    float acc = 0.f;
    #pragma unroll 8
    for (int k = 0; k < D; ++k)
        acc = fmaf(m[k], Wm[(k << 7) + d], acc);
    tg[(b << 7) + d] = fast_tanh(acc);
}

// Phase C: stream cached x2 (bf16), coef = sigmoid(<x2, tg[seg]>),
// out += coef*x2. No LDS/MFMA; tg row hoisted per segment; next-tile
// register prefetch. BW floor ~128 MB.
__global__ __launch_bounds__(THREADS, 4) void phaseC(
    const unsigned short* __restrict__ x2s, const int* __restrict__ batch,
    const float* __restrict__ tg, float* __restrict__ out, int N)
{
    const int lane = threadIdx.x & 63;
    const int wv = threadIdx.x >> 6;
    const int m15 = lane & 15;
    const int quad = lane >> 4;

    const int total16 = N >> 4;
    const int nw = BLOCKS_C * 4;
    const int gw = blockIdx.x * 4 + wv;
    const int base = total16 / nw, rem = total16 % nw;
    const int b0 = gw * base + (gw < rem ? gw : rem);
    const int b1e = b0 + base + (gw < rem ? 1 : 0);

    float acc[8], tgv[8];
    #pragma unroll
    for (int t = 0; t < 8; ++t) { acc[t] = 0.f; tgv[t] = 0.f; }
    int cur = -1;

    uint4 PK[4];
    if (b0 < b1e) {
        const uint4* p = (const uint4*)x2s + (size_t)b0 * 256 + lane;
        #pragma unroll
        for (int rg = 0; rg < 4; ++rg) PK[rg] = p[rg * 64];
    }

    for (int b = b0; b < b1e; ++b) {
        uint4 C[4];
        #pragma unroll
        for (int rg = 0; rg < 4; ++rg) C[rg] = PK[rg];
        if (b + 1 < b1e) {
            const uint4* p = (const uint4*)x2s + (size_t)(b + 1) * 256 + lane;
            #pragma unroll
            for (int rg = 0; rg < 4; ++rg) PK[rg] = p[rg * 64];
        }
        const int R = b << 4;
        #pragma unroll
        for (int rg = 0; rg < 4; ++rg) {
            int seg = batch[R + quad * 4 + rg];
            if (seg != cur) {
                if (cur >= 0) {
                    #pragma unroll
                    for (int t = 0; t < 8; ++t)
                        atomicAdd(&out[cur * 128 + m15 + 16 * t], acc[t]);
                }
                cur = seg;
                #pragma unroll
                for (int t = 0; t < 8; ++t) {
                    tgv[t] = tg[seg * 128 + m15 + 16 * t];
                    acc[t] = 0.f;
                }
            }
            float xv[8];
            unsigned w;
            union { unsigned u; float f; } cv;
            w = C[rg].x; cv.u = w << 16; xv[0] = cv.f; cv.u = w & 0xffff0000u; xv[1] = cv.f;
            w = C[rg].y; cv.u = w << 16; xv[2] = cv.f; cv.u = w & 0xffff0000u; xv[3] = cv.f;
            w = C[rg].z; cv.u = w << 16; xv[4] = cv.f; cv.u = w & 0xffff0000u; xv[5] = cv.f;
            w = C[rg].w; cv.u = w << 16; xv[6] = cv.f; cv.u = w & 0xffff0000u; xv[7] = cv.f;
            float dot = 0.f;
            #pragma unroll
            for (int t = 0; t < 8; ++t) dot = fmaf(xv[t], tgv[t], dot);
            dot += __shfl_xor(dot, 1);
            dot += __shfl_xor(dot, 2);
            dot += __shfl_xor(dot, 4);
            dot += __shfl_xor(dot, 8);
            float coef = 1.f / (1.f + __expf(-dot));
            #pragma unroll
            for (int t = 0; t < 8; ++t) acc[t] = fmaf(coef, xv[t], acc[t]);
        }
    }
    if (cur >= 0) {
        #pragma unroll
        for (int t = 0; t < 8; ++t)
            atomicAdd(&out[cur * 128 + m15 + 16 * t], acc[t]);
    }
}

extern "C" void kernel_launch(void* const* d_in, const int* in_sizes, int n_in,
                              void* d_out, int out_size, void* d_ws, size_t ws_size,
                              hipStream_t stream) {
    const float* x     = (const float*)d_in[0];
    const int*   batch = (const int*)d_in[1];
    const float* Wm    = (const float*)d_in[3];
    const float* fc1_w = (const float*)d_in[4];
    const float* fc1_b = (const float*)d_in[5];
    const float* fc2_w = (const float*)d_in[6];
    const float* fc2_b = (const float*)d_in[7];
    float* out = (float*)d_out;

    int N = in_sizes[0] / D;
    int B = out_size / D;

    float* sums = (float*)d_ws;                        // [B,128]
    float* cnt  = sums + (size_t)B * D;                // [B]
    float* tg   = cnt + B;                             // [B,128]
    unsigned short* x2s = (unsigned short*)(tg + (size_t)B * D); // [N,128] bf16

    hipMemsetAsync(d_ws, 0, ((size_t)B * D + B) * sizeof(float), stream);
    hipMemsetAsync(d_out, 0, (size_t)out_size * sizeof(float), stream);

    phaseA<<<BLOCKS_A, THREADS, 0, stream>>>(
        x, batch, fc1_w, fc1_b, fc2_w, fc2_b, sums, cnt, x2s, N);
    phaseB<<<B, D, 0, stream>>>(sums, cnt, Wm, tg);
    phaseC<<<BLOCKS_C, THREADS, 0, stream>>>(x2s, batch, tg, out, N);
}